// Round 1
// baseline (122.039 us; speedup 1.0000x reference)
//
#include <hip/hip_runtime.h>

// DeepQNetwork fused forward:  x(B,15) -> onehot(36) -> 128 -> 512 -> 40
// All GEMMs via v_mfma_f32_16x16x32_bf16 (verified layouts):
//   A frag: lane holds A[m=lane&15][k=(lane>>4)*8+j], j=0..7  (16B contiguous)
//   B frag: lane holds B[k=(lane>>4)*8+j][n=lane&15]  -> prepacked fragment-linear
//   C/D:    lane reg r holds C[row=(lane>>4)*4+r][col=lane&15]

typedef short bf16x8 __attribute__((ext_vector_type(8)));
typedef float f32x4 __attribute__((ext_vector_type(4)));

#define NW1F 8192              // 8 ntiles * 2 ksteps * 512
#define NW2F 65536             // 32 ntiles * 4 ksteps * 512
#define NW4F 24576             // 3 ntiles * 16 ksteps * 512
#define PACK_TOTAL (NW1F + NW2F + NW4F)   // 98304 shorts = 192 KB of ws

__device__ __forceinline__ unsigned short f2bf(float f) {
  union { float f; unsigned u; } a; a.f = f;
  unsigned r = a.u + 0x7fffu + ((a.u >> 16) & 1u);   // RNE (no NaN inputs here)
  return (unsigned short)(r >> 16);
}

// Prepack W1 (36x128, K-padded to 64), W2 (128x512), W4 (512x40, N-padded to 48)
// into bf16 B-fragment-linear order: frag*512 + lane*8 + j.
__global__ void pack_weights(const float* __restrict__ W1,
                             const float* __restrict__ W2,
                             const float* __restrict__ W4,
                             unsigned short* __restrict__ wf) {
  int id = blockIdx.x * 256 + threadIdx.x;
  if (id >= PACK_TOTAL) return;
  if (id < NW1F) {
    int frag = id >> 9, rem = id & 511;
    int lane = rem >> 3, j = rem & 7;
    int nt = frag >> 1, ks = frag & 1;
    int k = ks * 32 + (lane >> 4) * 8 + j;
    int n = nt * 16 + (lane & 15);
    wf[id] = f2bf(k < 36 ? W1[k * 128 + n] : 0.f);
  } else if (id < NW1F + NW2F) {
    int i2 = id - NW1F;
    int frag = i2 >> 9, rem = i2 & 511;
    int lane = rem >> 3, j = rem & 7;
    int nt = frag >> 2, ks = frag & 3;
    int k = ks * 32 + (lane >> 4) * 8 + j;
    int n = nt * 16 + (lane & 15);
    wf[id] = f2bf(W2[k * 512 + n]);
  } else {
    int i4 = id - (NW1F + NW2F);
    int frag = i4 >> 9, rem = i4 & 511;
    int lane = rem >> 3, j = rem & 7;
    int nt = frag >> 4, ks = frag & 15;
    int k = ks * 32 + (lane >> 4) * 8 + j;
    int n = nt * 16 + (lane & 15);
    wf[id] = f2bf(n < 40 ? W4[k * 40 + n] : 0.f);
  }
}

// 256 threads = 4 waves; each wave privately owns 32 rows (2 M-tiles).
// No __syncthreads anywhere: every LDS produce/consume pair is within one wave
// (DS ops execute in order per wave).
__global__ __launch_bounds__(256, 3) void dqn_fused(
    const float* __restrict__ x,
    const unsigned short* __restrict__ wf,
    const float* __restrict__ b1,
    const float* __restrict__ b2,
    const float* __restrict__ b4,
    float* __restrict__ out) {
  // per-wave scratch (union): onehot input [32][72]  OR  h2 chunk [32][72]
  __shared__ __align__(16) unsigned short sU[4 * 32 * 72];   // 18 KB
  __shared__ __align__(16) unsigned short sH1[128 * 136];    // 34 KB  (ld 136: 272B = 4 banks mod 32 -> 2-way, free)

  const int tid  = threadIdx.x;
  const int lane = tid & 63;
  const int wave = tid >> 6;
  const int quad = lane >> 4;
  const int l16  = lane & 15;
  const int row0 = blockIdx.x << 7;              // 128 rows per block
  const int lr0  = wave * 32;
  unsigned short* su = sU + wave * (32 * 72);    // wave-private

  // ---- stage 1: build one-hot input (bf16) in LDS, K padded 36->64 with 0 ----
  {
    const int lrow = (tid >> 1) & 31;            // row within wave
    const int half = (tid & 1) << 5;             // cols 0..31 or 32..63
    const float* xr = x + (size_t)(row0 + lr0 + lrow) * 15;
    int hold = (int)xr[11]; hold = hold < 0 ? 0 : (hold > 3 ? 3 : hold);
    int nx0 = (int)xr[12] - 1; nx0 = nx0 < 0 ? 0 : (nx0 > 6 ? 6 : nx0);
    int nx1 = (int)xr[13] - 1; nx1 = nx1 < 0 ? 0 : (nx1 > 6 ? 6 : nx1);
    int nx2 = (int)xr[14] - 1; nx2 = nx2 < 0 ? 0 : (nx2 > 6 ? 6 : nx2);
    unsigned short* dst = su + lrow * 72;
    for (int i = 0; i < 32; ++i) {
      int c = half + i;
      float v = 0.f;
      if (c < 11) v = xr[c];
      else if (c < 15) v = (c - 11 == hold) ? 1.f : 0.f;
      else if (c < 36) {
        int cc = c - 15;
        int t3 = cc / 7;
        int pp = cc - t3 * 7;
        int nx = (t3 == 0) ? nx0 : (t3 == 1 ? nx1 : nx2);
        v = (pp == nx) ? 1.f : 0.f;
      }
      dst[c] = f2bf(v);
    }
  }

  const f32x4 vzero = {0.f, 0.f, 0.f, 0.f};

  // ---- stage 2: L1 GEMM  h1[32][128] = relu(inp @ W1 + b1) -> sH1 (bf16) ----
  f32x4 acc1[2][8];
#pragma unroll
  for (int m = 0; m < 2; ++m)
#pragma unroll
    for (int nt = 0; nt < 8; ++nt) acc1[m][nt] = vzero;

#pragma unroll
  for (int ks = 0; ks < 2; ++ks) {
    bf16x8 a0 = *(const bf16x8*)(su + (l16)      * 72 + ks * 32 + quad * 8);
    bf16x8 a1 = *(const bf16x8*)(su + (16 + l16) * 72 + ks * 32 + quad * 8);
#pragma unroll
    for (int nt = 0; nt < 8; ++nt) {
      bf16x8 b = *(const bf16x8*)(wf + ((nt * 2 + ks) * 64 + lane) * 8);
      acc1[0][nt] = __builtin_amdgcn_mfma_f32_16x16x32_bf16(a0, b, acc1[0][nt], 0, 0, 0);
      acc1[1][nt] = __builtin_amdgcn_mfma_f32_16x16x32_bf16(a1, b, acc1[1][nt], 0, 0, 0);
    }
  }
#pragma unroll
  for (int nt = 0; nt < 8; ++nt) {
    float bias = b1[nt * 16 + l16];
#pragma unroll
    for (int m = 0; m < 2; ++m)
#pragma unroll
      for (int r = 0; r < 4; ++r) {
        float v = acc1[m][nt][r] + bias;
        sH1[(lr0 + m * 16 + quad * 4 + r) * 136 + nt * 16 + l16] = f2bf(v > 0.f ? v : 0.f);
      }
  }

  // ---- stage 3: cache h1 A-frags, then fused L2+L3 over 8 chunks of 64 cols ----
  bf16x8 af1[2][4];
#pragma unroll
  for (int m = 0; m < 2; ++m)
#pragma unroll
    for (int ks = 0; ks < 4; ++ks)
      af1[m][ks] = *(const bf16x8*)(sH1 + (lr0 + m * 16 + l16) * 136 + ks * 32 + quad * 8);

  f32x4 accO[2][3];
#pragma unroll
  for (int m = 0; m < 2; ++m)
#pragma unroll
    for (int nt = 0; nt < 3; ++nt) accO[m][nt] = vzero;

  const unsigned short* w2f = wf + NW1F;
  const unsigned short* w4f = wf + NW1F + NW2F;

  for (int chunk = 0; chunk < 8; ++chunk) {
    f32x4 acc2[2][4];
#pragma unroll
    for (int m = 0; m < 2; ++m)
#pragma unroll
      for (int nt = 0; nt < 4; ++nt) acc2[m][nt] = vzero;

#pragma unroll
    for (int ks = 0; ks < 4; ++ks) {
#pragma unroll
      for (int nt = 0; nt < 4; ++nt) {
        bf16x8 b = *(const bf16x8*)(w2f + (((chunk * 4 + nt) * 4 + ks) * 64 + lane) * 8);
        acc2[0][nt] = __builtin_amdgcn_mfma_f32_16x16x32_bf16(af1[0][ks], b, acc2[0][nt], 0, 0, 0);
        acc2[1][nt] = __builtin_amdgcn_mfma_f32_16x16x32_bf16(af1[1][ks], b, acc2[1][nt], 0, 0, 0);
      }
    }
    // bias + relu -> h2 chunk (bf16, A-layout-ready) in wave-private su
#pragma unroll
    for (int nt = 0; nt < 4; ++nt) {
      float bias = b2[chunk * 64 + nt * 16 + l16];
#pragma unroll
      for (int m = 0; m < 2; ++m)
#pragma unroll
        for (int r = 0; r < 4; ++r) {
          float v = acc2[m][nt][r] + bias;
          su[(m * 16 + quad * 4 + r) * 72 + nt * 16 + l16] = f2bf(v > 0.f ? v : 0.f);
        }
    }
    // L3 partial: out[32][48] += h2chunk @ W4[chunk rows]
#pragma unroll
    for (int ks3 = 0; ks3 < 2; ++ks3) {
      bf16x8 a0 = *(const bf16x8*)(su + (l16)      * 72 + ks3 * 32 + quad * 8);
      bf16x8 a1 = *(const bf16x8*)(su + (16 + l16) * 72 + ks3 * 32 + quad * 8);
#pragma unroll
      for (int nt3 = 0; nt3 < 3; ++nt3) {
        bf16x8 b = *(const bf16x8*)(w4f + ((nt3 * 16 + chunk * 2 + ks3) * 64 + lane) * 8);
        accO[0][nt3] = __builtin_amdgcn_mfma_f32_16x16x32_bf16(a0, b, accO[0][nt3], 0, 0, 0);
        accO[1][nt3] = __builtin_amdgcn_mfma_f32_16x16x32_bf16(a1, b, accO[1][nt3], 0, 0, 0);
      }
    }
  }

  // ---- epilogue: + b4, store fp32 (cols 40..47 are padding) ----
#pragma unroll
  for (int nt3 = 0; nt3 < 3; ++nt3) {
    int col = nt3 * 16 + l16;
    if (col < 40) {
      float bias = b4[col];
#pragma unroll
      for (int m = 0; m < 2; ++m)
#pragma unroll
        for (int r = 0; r < 4; ++r) {
          size_t row = (size_t)(row0 + lr0 + m * 16 + quad * 4 + r);
          out[row * 40 + col] = accO[m][nt3][r] + bias;
        }
    }
  }
}

extern "C" void kernel_launch(void* const* d_in, const int* in_sizes, int n_in,
                              void* d_out, int out_size, void* d_ws, size_t ws_size,
                              hipStream_t stream) {
  const float* x  = (const float*)d_in[0];
  const float* W1 = (const float*)d_in[1];
  const float* b1 = (const float*)d_in[2];
  const float* W2 = (const float*)d_in[3];
  const float* b2 = (const float*)d_in[4];
  const float* W4 = (const float*)d_in[5];
  const float* b4 = (const float*)d_in[6];
  float* out = (float*)d_out;
  unsigned short* wf = (unsigned short*)d_ws;   // needs 192 KB of ws

  int B = in_sizes[0] / 15;

  hipLaunchKernelGGL(pack_weights, dim3((PACK_TOTAL + 255) / 256), dim3(256), 0, stream,
                     W1, W2, W4, wf);
  hipLaunchKernelGGL(dqn_fused, dim3(B / 128), dim3(256), 0, stream,
                     x, wf, b1, b2, b4, out);
}

// Round 2
// 114.610 us; speedup vs baseline: 1.0648x; 1.0648x over previous
//
#include <hip/hip_runtime.h>

// DeepQNetwork fused forward:  x(B,15) -> onehot(36) -> 128 -> 512 -> 40
// R2: ALL GEMMs transposed (features = M, batch rows = N):
//     h^T = W^T @ x^T   via v_mfma_f32_16x16x32_bf16
//   A frag (weights, prepacked): lane holds A[m=l16][k=quad*8+j] (16B contig in ws)
//   B frag (activations):        lane holds B[k=quad*8+j][n=l16] = act[row=n][feat k]
//                                -> ds_read_b128 from row-major [row][feat] LDS
//   C/D: lane reg r holds D[m=quad*4+r][n=l16] = 4 CONSECUTIVE FEATURES, fixed row
//                                -> pack 4 bf16 -> ONE ds_write_b64 back to [row][feat]
// This makes the inter-layer layout transform vectorized on BOTH sides
// (R1 used 256 scalar ds_write_b16 per thread -> 1.5M bank-conflict cycles).

typedef short bf16x8 __attribute__((ext_vector_type(8)));
typedef float f32x4 __attribute__((ext_vector_type(4)));
typedef unsigned int u32;

#define NW1F 8192              // 8 mt * 2 ks * 512
#define NW2F 65536             // 32 mt * 4 ks * 512
#define NW4F 24576             // 3 mt * 16 ks * 512
#define PACK_TOTAL (NW1F + NW2F + NW4F)   // 98304 shorts = 192 KB of ws

__device__ __forceinline__ unsigned short f2bf(float f) {
  union { float f; unsigned u; } a; a.f = f;
  unsigned r = a.u + 0x7fffu + ((a.u >> 16) & 1u);   // RNE (no NaN inputs here)
  return (unsigned short)(r >> 16);
}
__device__ __forceinline__ u32 pack2bf(float a, float b) {
  return (u32)f2bf(a) | ((u32)f2bf(b) << 16);
}

// Prepack W1^T (128x64, K-pad 36->64), W2^T (512x128), W4^T (48x512, M-pad 40->48)
// as A-fragment-linear bf16: frag*512 + lane*8 + j, A[m=mt*16+l16][k=ks*32+quad*8+j].
__global__ void pack_weights(const float* __restrict__ W1,
                             const float* __restrict__ W2,
                             const float* __restrict__ W4,
                             unsigned short* __restrict__ wf) {
  int id = blockIdx.x * 256 + threadIdx.x;
  if (id >= PACK_TOTAL) return;
  int rem = id & 511, lane = rem >> 3, j = rem & 7;
  int l16 = lane & 15, quad = lane >> 4;
  if (id < NW1F) {
    int frag = id >> 9;                 // mt*2 + ks, mt<8, ks<2
    int mt = frag >> 1, ks = frag & 1;
    int m = mt * 16 + l16, k = ks * 32 + quad * 8 + j;
    wf[id] = f2bf(k < 36 ? W1[k * 128 + m] : 0.f);     // W1^T[m][k] = W1[k][m]
  } else if (id < NW1F + NW2F) {
    int frag = (id - NW1F) >> 9;        // mt*4 + ks, mt<32, ks<4
    int mt = frag >> 2, ks = frag & 3;
    int m = mt * 16 + l16, k = ks * 32 + quad * 8 + j;
    wf[id] = f2bf(W2[k * 512 + m]);
  } else {
    int frag = (id - NW1F - NW2F) >> 9; // mt*16 + ks, mt<3, ks<16
    int mt = frag >> 4, ks = frag & 15;
    int m = mt * 16 + l16, k = ks * 32 + quad * 8 + j;
    wf[id] = f2bf(m < 40 ? W4[k * 40 + m] : 0.f);
  }
}

// 256 threads = 4 waves; each wave privately owns 32 rows (2 N-groups of 16).
// Zero barriers: every LDS produce/consume pair is within one wave (DS in-order).
__global__ __launch_bounds__(256, 3) void dqn_fused(
    const float* __restrict__ x,
    const unsigned short* __restrict__ wf,
    const float* __restrict__ b1,
    const float* __restrict__ b2,
    const float* __restrict__ b4,
    float* __restrict__ out) {
  // per-wave: onehot input [32][72] (reused as h2 chunk [32 rows][64 feats])
  __shared__ __align__(16) unsigned short sU[4 * 32 * 72];    // 18.4 KB
  // per-wave: h1 [32 rows][128 feats] stride 136 (272B = 16B-mult, conflict-free)
  __shared__ __align__(16) unsigned short sH1[4 * 32 * 136];  // 34.8 KB

  const int tid  = threadIdx.x;
  const int lane = tid & 63;
  const int wave = tid >> 6;
  const int quad = lane >> 4;
  const int l16  = lane & 15;
  const int row0 = blockIdx.x << 7;              // 128 rows per block
  const int lr0  = wave * 32;
  unsigned short* su  = sU  + wave * (32 * 72);
  unsigned short* sh1 = sH1 + wave * (32 * 136);

  // ---- stage 1: one-hot input rows in LDS (bf16), K padded 36->64 ----
  if (lane < 32) {
    const float* xr = x + (size_t)(row0 + lr0 + lane) * 15;
    unsigned short* dst = su + lane * 72;
    bf16x8 z = {0, 0, 0, 0, 0, 0, 0, 0};
#pragma unroll
    for (int c = 8; c < 64; c += 8) *(bf16x8*)(dst + c) = z;   // zero cols 8..63
    // keep cols 0..7 (one b128 write)
    u32 p[4];
#pragma unroll
    for (int i = 0; i < 4; ++i) p[i] = pack2bf(xr[2 * i], xr[2 * i + 1]);
    *(bf16x8*)dst = *(bf16x8*)p;
    // keep cols 8..10 (over the zeroed region)
    *(u32*)(dst + 8) = pack2bf(xr[8], xr[9]);
    dst[10] = f2bf(xr[10]);
    // one-hots: bf16 1.0 = 0x3F80
    int hold = (int)xr[11]; hold = hold < 0 ? 0 : (hold > 3 ? 3 : hold);
    dst[11 + hold] = 0x3F80;
#pragma unroll
    for (int t = 0; t < 3; ++t) {
      int nx = (int)xr[12 + t] - 1; nx = nx < 0 ? 0 : (nx > 6 ? 6 : nx);
      dst[15 + t * 7 + nx] = 0x3F80;
    }
  }

  const f32x4 vzero = {0.f, 0.f, 0.f, 0.f};

  // ---- stage 2: h1^T = W1^T @ inp^T ;  h1 -> sh1 (bf16, [row][feat]) ----
  bf16x8 ib[2][2];
#pragma unroll
  for (int rg = 0; rg < 2; ++rg)
#pragma unroll
    for (int ks = 0; ks < 2; ++ks)
      ib[rg][ks] = *(const bf16x8*)(su + (rg * 16 + l16) * 72 + ks * 32 + quad * 8);

  f32x4 acc1[8][2];
#pragma unroll
  for (int mt = 0; mt < 8; ++mt) { acc1[mt][0] = vzero; acc1[mt][1] = vzero; }
#pragma unroll
  for (int mt = 0; mt < 8; ++mt)
#pragma unroll
    for (int ks = 0; ks < 2; ++ks) {
      bf16x8 wa = *(const bf16x8*)(wf + (size_t)((mt * 2 + ks) * 64 + lane) * 8);
      acc1[mt][0] = __builtin_amdgcn_mfma_f32_16x16x32_bf16(wa, ib[0][ks], acc1[mt][0], 0, 0, 0);
      acc1[mt][1] = __builtin_amdgcn_mfma_f32_16x16x32_bf16(wa, ib[1][ks], acc1[mt][1], 0, 0, 0);
    }
#pragma unroll
  for (int mt = 0; mt < 8; ++mt) {
    f32x4 bias = *(const f32x4*)(b1 + mt * 16 + quad * 4);
#pragma unroll
    for (int rg = 0; rg < 2; ++rg) {
      float v0 = fmaxf(acc1[mt][rg][0] + bias[0], 0.f);
      float v1 = fmaxf(acc1[mt][rg][1] + bias[1], 0.f);
      float v2 = fmaxf(acc1[mt][rg][2] + bias[2], 0.f);
      float v3 = fmaxf(acc1[mt][rg][3] + bias[3], 0.f);
      u32 p0 = pack2bf(v0, v1), p1 = pack2bf(v2, v3);
      uint2 pk = {p0, p1};
      *(uint2*)(sh1 + (rg * 16 + l16) * 136 + mt * 16 + quad * 4) = pk;  // b64, 4 feats
    }
  }

  // ---- stage 3: cache h1 B-frags in regs ----
  bf16x8 af1[2][4];
#pragma unroll
  for (int rg = 0; rg < 2; ++rg)
#pragma unroll
    for (int ks = 0; ks < 4; ++ks)
      af1[rg][ks] = *(const bf16x8*)(sh1 + (rg * 16 + l16) * 136 + ks * 32 + quad * 8);

  f32x4 accO[3][2];
#pragma unroll
  for (int mt = 0; mt < 3; ++mt) { accO[mt][0] = vzero; accO[mt][1] = vzero; }

  const unsigned short* w2f = wf + NW1F;
  const unsigned short* w4f = wf + NW1F + NW2F;

  // ---- stage 4+5: per 64-feat chunk: h2^T = W2^T @ h1^T ; O^T += W4^T @ h2^T ----
  for (int chunk = 0; chunk < 8; ++chunk) {
    f32x4 acc2[4][2];
#pragma unroll
    for (int mtl = 0; mtl < 4; ++mtl) { acc2[mtl][0] = vzero; acc2[mtl][1] = vzero; }

#pragma unroll
    for (int ks = 0; ks < 4; ++ks)
#pragma unroll
      for (int mtl = 0; mtl < 4; ++mtl) {
        bf16x8 w = *(const bf16x8*)(w2f + (size_t)((((chunk * 4 + mtl) * 4) + ks) * 64 + lane) * 8);
        acc2[mtl][0] = __builtin_amdgcn_mfma_f32_16x16x32_bf16(w, af1[0][ks], acc2[mtl][0], 0, 0, 0);
        acc2[mtl][1] = __builtin_amdgcn_mfma_f32_16x16x32_bf16(w, af1[1][ks], acc2[mtl][1], 0, 0, 0);
      }
    // bias+relu, pack 4 feats -> one b64 write per (mtl, rg)
#pragma unroll
    for (int mtl = 0; mtl < 4; ++mtl) {
      f32x4 bias = *(const f32x4*)(b2 + chunk * 64 + mtl * 16 + quad * 4);
#pragma unroll
      for (int rg = 0; rg < 2; ++rg) {
        float v0 = fmaxf(acc2[mtl][rg][0] + bias[0], 0.f);
        float v1 = fmaxf(acc2[mtl][rg][1] + bias[1], 0.f);
        float v2 = fmaxf(acc2[mtl][rg][2] + bias[2], 0.f);
        float v3 = fmaxf(acc2[mtl][rg][3] + bias[3], 0.f);
        uint2 pk = {pack2bf(v0, v1), pack2bf(v2, v3)};
        *(uint2*)(su + (rg * 16 + l16) * 72 + mtl * 16 + quad * 4) = pk;
      }
    }
    // L3 partial on this chunk's 64 feats
#pragma unroll
    for (int ks3 = 0; ks3 < 2; ++ks3) {
      bf16x8 h0 = *(const bf16x8*)(su + (l16)      * 72 + ks3 * 32 + quad * 8);
      bf16x8 h1f = *(const bf16x8*)(su + (16 + l16) * 72 + ks3 * 32 + quad * 8);
#pragma unroll
      for (int mt3 = 0; mt3 < 3; ++mt3) {
        bf16x8 w = *(const bf16x8*)(w4f + (size_t)((mt3 * 16 + chunk * 2 + ks3) * 64 + lane) * 8);
        accO[mt3][0] = __builtin_amdgcn_mfma_f32_16x16x32_bf16(w, h0,  accO[mt3][0], 0, 0, 0);
        accO[mt3][1] = __builtin_amdgcn_mfma_f32_16x16x32_bf16(w, h1f, accO[mt3][1], 0, 0, 0);
      }
    }
  }

  // ---- epilogue: +b4, float4 stores (lane holds 4 consecutive out-cols) ----
#pragma unroll
  for (int mt3 = 0; mt3 < 3; ++mt3) {
    int colbase = mt3 * 16 + quad * 4;
    if (colbase < 40) {                      // drops mt3==2, quad>=2 (pad cols)
      f32x4 bias = *(const f32x4*)(b4 + colbase);
#pragma unroll
      for (int rg = 0; rg < 2; ++rg) {
        f32x4 v = accO[mt3][rg] + bias;
        size_t row = (size_t)(row0 + lr0 + rg * 16 + l16);
        *(f32x4*)(out + row * 40 + colbase) = v;
      }
    }
  }
}

extern "C" void kernel_launch(void* const* d_in, const int* in_sizes, int n_in,
                              void* d_out, int out_size, void* d_ws, size_t ws_size,
                              hipStream_t stream) {
  const float* x  = (const float*)d_in[0];
  const float* W1 = (const float*)d_in[1];
  const float* b1 = (const float*)d_in[2];
  const float* W2 = (const float*)d_in[3];
  const float* b2 = (const float*)d_in[4];
  const float* W4 = (const float*)d_in[5];
  const float* b4 = (const float*)d_in[6];
  float* out = (float*)d_out;
  unsigned short* wf = (unsigned short*)d_ws;   // 192 KB of ws

  int B = in_sizes[0] / 15;

  hipLaunchKernelGGL(pack_weights, dim3((PACK_TOTAL + 255) / 256), dim3(256), 0, stream,
                     W1, W2, W4, wf);
  hipLaunchKernelGGL(dqn_fused, dim3(B / 128), dim3(256), 0, stream,
                     x, wf, b1, b2, b4, out);
}